// Round 1
// baseline (49842.166 us; speedup 1.0000x reference)
//
#include <hip/hip_runtime.h>

// LSTM autoencoder, persistent cooperative-style kernel (plain launch,
// 256 blocks x 256 threads = 1 block/CU => all blocks co-resident).
//
// Shapes: B=128, T=128, F=128, D=512, 4D=2048.
// Phase plan (513 grid barriers):
//   P0: Wsum = enc_W1+enc_U1 ; WdecA = dense_W@dec_W0 + dec_U0 ; bfold = dense_b@dec_W0 + dec_b0
//   enc t=0..127:  A: (x_t,h)->h1,c1        B: h1@Wsum -> h,c
//   dec t=0:       A: (dec_in0,h)->hA       B: (hA,h)->h,c
//   dec t=1..127:  A': h@WdecA -> hA  (+ emit out_{t-1} = h@dense_W)   B: (hA,h)->h,c
//   final: emit out_127
// outs are time-reversed: out_t -> row (T-1-t).

#define Bsz 128
#define Tsz 128
#define Fsz 128
#define Dsz 512
#define ND  2048
#define NBLK 256
#define NTHR 256
#define NTOT (NBLK*NTHR)

// ws layout (floats)
#define OFF_H0    64
#define OFF_C0    (64 + 65536)
#define OFF_H1    (64 + 2*65536)
#define OFF_C1    (64 + 3*65536)
#define OFF_HM    (64 + 4*65536)
#define OFF_CM    (64 + 5*65536)
#define OFF_WSUM  (64 + 6*65536)
#define OFF_WDECA (OFF_WSUM + Dsz*ND)
#define OFF_BFOLD (OFF_WDECA + Dsz*ND)

__device__ __forceinline__ float sigf(float x) {
    return 1.0f / (1.0f + __expf(-x));
}

// grid barrier: monotone arrive counter in ws, agent-scope atomics.
__device__ __forceinline__ void gbar(unsigned* cnt, unsigned target) {
    __syncthreads();
    if (threadIdx.x == 0) {
        __threadfence();  // release all prior global stores (agent scope)
        __hip_atomic_fetch_add(cnt, 1u, __ATOMIC_ACQ_REL, __HIP_MEMORY_SCOPE_AGENT);
        while (__hip_atomic_load(cnt, __ATOMIC_ACQUIRE, __HIP_MEMORY_SCOPE_AGENT) < target) {
            __builtin_amdgcn_s_sleep(1);
        }
    }
    __syncthreads();
}

// One LSTM cell phase. Computes, for this thread's (b,d):
//   z_g = bias[g*D+d] + sum_k x0[b,k]*W0[k,g*D+d] (+ sum_k x1[b,k]*W1[k,g*D+d])
//   i=sig, f=sig, g=relu, o=sig ; c2 = f*cprev + i*g ; h2 = o*relu(c2)
// Block tile: 32 b x 8 d. gates laid out [i|f|g|o] along the 2048 axis.
__device__ void cell_phase(const float* x0, int ld0, int K0, const float* W0,
                           const float* x1, int K1, const float* W1,
                           const float* bias, const float* cprev,
                           float* hout, float* cout)
{
    const int lb  = threadIdx.x >> 3;
    const int ldd = threadIdx.x & 7;
    const int b   = (blockIdx.x >> 6) * 32 + lb;
    const int d   = (blockIdx.x & 63) * 8 + ldd;

    float zi = bias[d];
    float zf = bias[Dsz + d];
    float zg = bias[2*Dsz + d];
    float zo = bias[3*Dsz + d];

    {
        const float* xr = x0 + (size_t)b * ld0;
        const float* wb = W0 + d;
        for (int k = 0; k < K0; k += 4) {
            float4 xv = *(const float4*)(xr + k);
            const float* w = wb + (size_t)k * ND;
            zi += xv.x*w[0]        + xv.y*w[ND]          + xv.z*w[2*ND]          + xv.w*w[3*ND];
            zf += xv.x*w[Dsz]      + xv.y*w[ND+Dsz]      + xv.z*w[2*ND+Dsz]      + xv.w*w[3*ND+Dsz];
            zg += xv.x*w[2*Dsz]    + xv.y*w[ND+2*Dsz]    + xv.z*w[2*ND+2*Dsz]    + xv.w*w[3*ND+2*Dsz];
            zo += xv.x*w[3*Dsz]    + xv.y*w[ND+3*Dsz]    + xv.z*w[2*ND+3*Dsz]    + xv.w*w[3*ND+3*Dsz];
        }
    }
    if (x1 != nullptr) {
        const float* xr = x1 + (size_t)b * Dsz;
        const float* wb = W1 + d;
        for (int k = 0; k < K1; k += 4) {
            float4 xv = *(const float4*)(xr + k);
            const float* w = wb + (size_t)k * ND;
            zi += xv.x*w[0]        + xv.y*w[ND]          + xv.z*w[2*ND]          + xv.w*w[3*ND];
            zf += xv.x*w[Dsz]      + xv.y*w[ND+Dsz]      + xv.z*w[2*ND+Dsz]      + xv.w*w[3*ND+Dsz];
            zg += xv.x*w[2*Dsz]    + xv.y*w[ND+2*Dsz]    + xv.z*w[2*ND+2*Dsz]    + xv.w*w[3*ND+2*Dsz];
            zo += xv.x*w[3*Dsz]    + xv.y*w[ND+3*Dsz]    + xv.z*w[2*ND+3*Dsz]    + xv.w*w[3*ND+3*Dsz];
        }
    }

    float gi = sigf(zi);
    float gf = sigf(zf);
    float gg = fmaxf(zg, 0.0f);
    float go = sigf(zo);
    float c2 = gf * cprev[(size_t)b*Dsz + d] + gi * gg;
    float h2 = go * fmaxf(c2, 0.0f);
    hout[(size_t)b*Dsz + d] = h2;
    if (cout) cout[(size_t)b*Dsz + d] = c2;
}

// out row emit: out[b, tt, :] = h[b,:] @ dense_W + dense_b   (blocks 192..255 only)
__device__ void out_emit(const float* h, const float* dw, const float* db,
                         float* outp, int tt)
{
    if (blockIdx.x >= 192) {
        int gid = (blockIdx.x - 192) * NTHR + threadIdx.x;   // 0..16383
        int b = gid >> 7;
        int f = gid & 127;
        const float* hr = h + (size_t)b * Dsz;
        const float* w  = dw + f;
        float acc = db[f];
        for (int k = 0; k < Dsz; k += 4) {
            float4 hv = *(const float4*)(hr + k);
            acc += hv.x*w[(k+0)*Fsz] + hv.y*w[(k+1)*Fsz]
                 + hv.z*w[(k+2)*Fsz] + hv.w*w[(k+3)*Fsz];
        }
        outp[((size_t)b*Tsz + tt)*Fsz + f] = acc;
    }
}

__global__ void __launch_bounds__(NTHR)
lstm_ae_kernel(const float* enc_in, const float* dec_in,
               const float* eW0, const float* eU0, const float* eb0,
               const float* eW1, const float* eU1, const float* eb1,
               const float* dW0, const float* dU0, const float* db0,
               const float* dW1, const float* dU1, const float* db1,
               const float* dw,  const float* db,
               float* out, float* ws)
{
    unsigned* cnt = (unsigned*)ws;
    float* H[2]  = { ws + OFF_H0, ws + OFF_H1 };
    float* C[2]  = { ws + OFF_C0, ws + OFF_C1 };
    float* HM    = ws + OFF_HM;
    float* CM    = ws + OFF_CM;
    float* Wsum  = ws + OFF_WSUM;
    float* WdecA = ws + OFF_WDECA;
    float* bfold = ws + OFF_BFOLD;

    const int gid = blockIdx.x * NTHR + threadIdx.x;
    unsigned nb = 0;

    // ---- P0: precompute folded weights ----
    for (int i = gid; i < Dsz*ND; i += NTOT)
        Wsum[i] = eW1[i] + eU1[i];
    for (int u = gid; u < Dsz*ND; u += NTOT) {
        int k = u >> 11;            // 0..511
        int col = u & (ND - 1);     // 0..2047
        float acc = dU0[u];
        const float* dwr = dw + k * Fsz;
        for (int j = 0; j < Fsz; ++j)
            acc += dwr[j] * dW0[(size_t)j*ND + col];
        WdecA[u] = acc;
    }
    if (gid < ND) {
        float acc = db0[gid];
        for (int j = 0; j < Fsz; ++j)
            acc += db[j] * dW0[(size_t)j*ND + gid];
        bfold[gid] = acc;
    }
    gbar(cnt, ++nb * NBLK);

    int cur = 0;

    // ---- encoder: 128 steps, 2 phases each ----
    for (int t = 0; t < Tsz; ++t) {
        // layer0: x_t@eW0 + h@eU0 -> h1(HM), c1(CM)
        cell_phase(enc_in + (size_t)t*Fsz, Tsz*Fsz, Fsz, eW0,
                   H[cur], Dsz, eU0, eb0, C[cur], HM, CM);
        gbar(cnt, ++nb * NBLK);
        // layer1 (x=h=h1): h1@Wsum -> h,c (next)
        cell_phase(HM, Dsz, Dsz, Wsum, nullptr, 0, nullptr,
                   eb1, CM, H[cur^1], C[cur^1]);
        gbar(cnt, ++nb * NBLK);
        cur ^= 1;
    }

    // ---- decoder t=0 (unfolded; input = dec_in[:,0,:]) ----
    cell_phase(dec_in, Tsz*Fsz, Fsz, dW0,
               H[cur], Dsz, dU0, db0, C[cur], HM, nullptr);
    gbar(cnt, ++nb * NBLK);
    cell_phase(HM, Dsz, Dsz, dW1, H[cur], Dsz, dU1,
               db1, C[cur], H[cur^1], C[cur^1]);
    gbar(cnt, ++nb * NBLK);
    cur ^= 1;

    // ---- decoder t=1..127 (folded input) ----
    for (int t = 1; t < Tsz; ++t) {
        // layer0 folded: h@WdecA + bfold -> hA(HM); also emit out_{t-1} at row (T-t)
        cell_phase(H[cur], Dsz, Dsz, WdecA, nullptr, 0, nullptr,
                   bfold, C[cur], HM, nullptr);
        out_emit(H[cur], dw, db, out, Tsz - t);
        gbar(cnt, ++nb * NBLK);
        // layer1: hA@dW1 + h@dU1 -> h,c (next)
        cell_phase(HM, Dsz, Dsz, dW1, H[cur], Dsz, dU1,
                   db1, C[cur], H[cur^1], C[cur^1]);
        gbar(cnt, ++nb * NBLK);
        cur ^= 1;
    }

    // ---- final: out_127 -> row 0 ----
    out_emit(H[cur], dw, db, out, 0);
}

extern "C" void kernel_launch(void* const* d_in, const int* in_sizes, int n_in,
                              void* d_out, int out_size, void* d_ws, size_t ws_size,
                              hipStream_t stream) {
    (void)in_sizes; (void)n_in; (void)out_size; (void)ws_size;
    const float* enc_in = (const float*)d_in[0];
    const float* dec_in = (const float*)d_in[1];
    const float* eW0 = (const float*)d_in[2];
    const float* eU0 = (const float*)d_in[3];
    const float* eb0 = (const float*)d_in[4];
    const float* eW1 = (const float*)d_in[5];
    const float* eU1 = (const float*)d_in[6];
    const float* eb1 = (const float*)d_in[7];
    const float* dW0 = (const float*)d_in[8];
    const float* dU0 = (const float*)d_in[9];
    const float* db0 = (const float*)d_in[10];
    const float* dW1 = (const float*)d_in[11];
    const float* dU1 = (const float*)d_in[12];
    const float* db1 = (const float*)d_in[13];
    const float* dw  = (const float*)d_in[14];
    const float* db  = (const float*)d_in[15];
    float* out = (float*)d_out;
    float* ws  = (float*)d_ws;

    // zero: barrier counter (64 floats) + H0 + C0 (h0 = c0 = 0)
    hipMemsetAsync(d_ws, 0, (size_t)(64 + 2*65536) * sizeof(float), stream);

    lstm_ae_kernel<<<NBLK, NTHR, 0, stream>>>(
        enc_in, dec_in, eW0, eU0, eb0, eW1, eU1, eb1,
        dW0, dU0, db0, dW1, dU1, db1, dw, db, out, ws);
}